// Round 5
// baseline (51.539 us; speedup 1.0000x reference)
//
#include <hip/hip_runtime.h>

// LIF forward: x [T=32, B=64, N=16384] f32 -> spikes (0/1) f32, same shape.
// mem_t = mem_{t-1}*0.25 + x_t ; s_t = (mem_t > 1) ; reset mem on spike.
// Bit-exact vs numpy.
//
// R4 post-mortem: interleaved load_t/store_t share the in-order vmcnt
// counter -> using load_t's data waits on store_{t-1}'s ack (write
// backpressure) -> iteration time = store latency, not stream BW.
// (Evidence: fillBufferAligned writes at 7 TB/s with 10% occupancy; our
// mixed loop stuck at ~4.2 TB/s effective despite 48% occupancy.)
// Fix: issue ALL 32 loads first (8 KB/wave in flight), then compute the
// chain and stream stores. Scalar per thread keeps VGPR<=64 (8 waves/SIMD)
// and gives 4096 blocks for a smoother tail.

__global__ __launch_bounds__(256, 8) void lif_fwd_kernel(
    const float* __restrict__ x, float* __restrict__ out, int BN) {
    const size_t i = (size_t)blockIdx.x * 256 + threadIdx.x;

    // Phase 1: all loads issue back-to-back -- nothing older than a load
    // in the vmcnt queue, so compute retires them one at a time.
    float xv[32];
    #pragma unroll
    for (int t = 0; t < 32; ++t)
        xv[t] = x[(size_t)t * BN + i];

    // Phase 2: sequential LIF chain + store stream (stores are youngest
    // in the queue; they never block a load's retirement).
    float mem = 0.f;
    #pragma unroll
    for (int t = 0; t < 32; ++t) {
        mem = mem * 0.25f + xv[t];
        const float s = (mem > 1.0f) ? 1.0f : 0.0f;
        mem = (s != 0.0f) ? 0.0f : mem;
        out[(size_t)t * BN + i] = s;
    }
}

extern "C" void kernel_launch(void* const* d_in, const int* in_sizes, int n_in,
                              void* d_out, int out_size, void* d_ws, size_t ws_size,
                              hipStream_t stream) {
    const float* x = (const float*)d_in[0];
    float* out = (float*)d_out;

    const int T = 32;
    const int total = in_sizes[0];        // 33,554,432
    const int BN = total / T;             // 1,048,576 (divisible by 256)

    const int block = 256;
    const int grid = BN / block;          // 4096

    lif_fwd_kernel<<<grid, block, 0, stream>>>(x, out, BN);
}